// Round 5
// baseline (2300.454 us; speedup 1.0000x reference)
//
#include <hip/hip_runtime.h>
#include <hip/hip_bf16.h>

#define B_ 2
#define L_ 1024
#define D_ 1024
#define H_ 16
#define HD_ 64

static __device__ __forceinline__ float dot4(float4 a, float4 b) {
    return a.x * b.x + a.y * b.y + a.z * b.z + a.w * b.w;
}

// ---------------------------------------------------------------------------
// E (fp32, 2047x64) -> Efz (fp32, 2048x64) with a prepended zero row.
// rel[i,j] = q_i . E[j-i+L-2]; zero exactly when j-i = 1-L  =>  Efz[j-i+L-1]
// ---------------------------------------------------------------------------
__global__ __launch_bounds__(256) void conv_e_kernel(const float* __restrict__ E,
                                                     float* __restrict__ Efz) {
    int idx = blockIdx.x * 256 + threadIdx.x;
    if (idx < 64) Efz[idx] = 0.f;
    if (idx < 2047 * 64) Efz[64 + idx] = E[idx];
}

// ---------------------------------------------------------------------------
// Scalar LDS-tiled GEMM, all-fp32 (correctness-first round):
//   out[m][n] = (sum_k A[m][k]*W[n][k] + bias[n]) * alpha
// A: (2048,1024) fp32; W: (1024,1024) fp32 (N x K, torch-Linear W.T layout).
// 64x64 tile, 256 threads, 4x4 micro-tile, fp32 accumulate.
// ---------------------------------------------------------------------------
__global__ __launch_bounds__(256) void sgemm_bias_kernel(
    const float* __restrict__ A, const float* __restrict__ W,
    const float* __restrict__ bias, float* __restrict__ out, float alpha) {
    constexpr int N = D_;   // 1024
    constexpr int K = D_;   // 1024
    constexpr int BK = 16;

    __shared__ float As[BK][64 + 1];   // [k][m], +1 pad
    __shared__ float Ws[BK][64 + 1];   // [k][n]

    const int tid = threadIdx.x;
    const int m0 = blockIdx.y * 64;
    const int n0 = blockIdx.x * 64;
    const int tx = tid & 15;
    const int ty = tid >> 4;

    const int srow = tid >> 2;        // 0..63
    const int skk = (tid & 3) * 4;    // 0,4,8,12

    float acc[4][4] = {};

    for (int k0 = 0; k0 < K; k0 += BK) {
        {
            const float4 a = *(const float4*)&A[(size_t)(m0 + srow) * K + k0 + skk];
            As[skk + 0][srow] = a.x; As[skk + 1][srow] = a.y;
            As[skk + 2][srow] = a.z; As[skk + 3][srow] = a.w;
        }
        {
            const float4 w = *(const float4*)&W[(size_t)(n0 + srow) * K + k0 + skk];
            Ws[skk + 0][srow] = w.x; Ws[skk + 1][srow] = w.y;
            Ws[skk + 2][srow] = w.z; Ws[skk + 3][srow] = w.w;
        }
        __syncthreads();

#pragma unroll
        for (int k = 0; k < BK; ++k) {
            float av[4], wv[4];
#pragma unroll
            for (int i = 0; i < 4; ++i) av[i] = As[k][ty * 4 + i];
#pragma unroll
            for (int j = 0; j < 4; ++j) wv[j] = Ws[k][tx * 4 + j];
#pragma unroll
            for (int i = 0; i < 4; ++i)
#pragma unroll
                for (int j = 0; j < 4; ++j) acc[i][j] += av[i] * wv[j];
        }
        __syncthreads();
    }

#pragma unroll
    for (int i = 0; i < 4; ++i) {
        const int m = m0 + ty * 4 + i;
#pragma unroll
        for (int j = 0; j < 4; ++j) {
            const int n = n0 + tx * 4 + j;
            out[(size_t)m * N + n] = (acc[i][j] + bias[n]) * alpha;
        }
    }
}

// ---------------------------------------------------------------------------
// Attention (all fp32): one block per (bh, 4 query rows). Two-pass softmax.
// q pre-scaled by hd^-0.5. rel[i,j] = q_i . Efz[j-i+L-1] (row 0 is zeros).
// ---------------------------------------------------------------------------
__global__ __launch_bounds__(256) void attn_kernel(
    const float* __restrict__ qf, const float* __restrict__ kf,
    const float* __restrict__ vf, const float* __restrict__ Efz,
    float* __restrict__ ctx) {
    const int tid = threadIdx.x;
    const int bh = blockIdx.y;           // 0..31
    const int b = bh >> 4;
    const int h = bh & 15;
    const int i0 = blockIdx.x << 2;      // 4 query rows per block

    __shared__ __align__(16) float q_s[4][64];
    __shared__ __align__(16) float s_s[1024][4];   // [j][ii]
    __shared__ __align__(16) float4 red4[256];

    {
        const int ii = tid >> 6, d = tid & 63;
        q_s[ii][d] = qf[((size_t)(b * L_ + i0 + ii)) * D_ + h * HD_ + d];
    }
    __syncthreads();

    const float4* q4 = (const float4*)q_s;   // q4[ii*16 + c]

    float s[4][4];                            // [jj][ii]
#pragma unroll
    for (int jj = 0; jj < 4; ++jj)
#pragma unroll
        for (int ii = 0; ii < 4; ++ii) s[jj][ii] = 0.f;

    const float4* kp[4];
    int r1[4][4];
#pragma unroll
    for (int jj = 0; jj < 4; ++jj) {
        const int j = tid + (jj << 8);
        kp[jj] = (const float4*)(kf + ((size_t)(b * L_ + j)) * D_ + h * HD_);
#pragma unroll
        for (int ii = 0; ii < 4; ++ii) {
            r1[jj][ii] = j - (i0 + ii) + (L_ - 1);   // in [0, 2046]
        }
    }

#pragma unroll
    for (int d4 = 0; d4 < 16; ++d4) {
        float4 qa[4];
#pragma unroll
        for (int ii = 0; ii < 4; ++ii) qa[ii] = q4[ii * 16 + d4];
#pragma unroll
        for (int jj = 0; jj < 4; ++jj) {
            const float4 kv = kp[jj][d4];
#pragma unroll
            for (int ii = 0; ii < 4; ++ii) s[jj][ii] += dot4(qa[ii], kv);
        }
#pragma unroll
        for (int jj = 0; jj < 4; ++jj) {
#pragma unroll
            for (int ii = 0; ii < 4; ++ii) {
                const float4 ev =
                    *(const float4*)(Efz + (size_t)r1[jj][ii] * HD_ + d4 * 4);
                s[jj][ii] += dot4(qa[ii], ev);
            }
        }
    }

#pragma unroll
    for (int jj = 0; jj < 4; ++jj) {
        const int j = tid + (jj << 8);
        *(float4*)&s_s[j][0] = make_float4(s[jj][0], s[jj][1], s[jj][2], s[jj][3]);
    }
    __syncthreads();

    // ---- max reduce ----
    float4 mx = make_float4(-1e30f, -1e30f, -1e30f, -1e30f);
    for (int j = tid; j < L_; j += 256) {
        const float4 sv = *(const float4*)&s_s[j][0];
        mx.x = fmaxf(mx.x, sv.x); mx.y = fmaxf(mx.y, sv.y);
        mx.z = fmaxf(mx.z, sv.z); mx.w = fmaxf(mx.w, sv.w);
    }
    red4[tid] = mx;
    __syncthreads();
    for (int off = 128; off; off >>= 1) {
        if (tid < off) {
            float4 a = red4[tid], c = red4[tid + off];
            a.x = fmaxf(a.x, c.x); a.y = fmaxf(a.y, c.y);
            a.z = fmaxf(a.z, c.z); a.w = fmaxf(a.w, c.w);
            red4[tid] = a;
        }
        __syncthreads();
    }
    const float4 M4 = red4[0];
    __syncthreads();

    // ---- exp + sum ----
    float4 ls = make_float4(0.f, 0.f, 0.f, 0.f);
    for (int j = tid; j < L_; j += 256) {
        float4 sv = *(const float4*)&s_s[j][0];
        sv.x = __expf(sv.x - M4.x); sv.y = __expf(sv.y - M4.y);
        sv.z = __expf(sv.z - M4.z); sv.w = __expf(sv.w - M4.w);
        *(float4*)&s_s[j][0] = sv;
        ls.x += sv.x; ls.y += sv.y; ls.z += sv.z; ls.w += sv.w;
    }
    red4[tid] = ls;
    __syncthreads();
    for (int off = 128; off; off >>= 1) {
        if (tid < off) {
            float4 a = red4[tid], c = red4[tid + off];
            a.x += c.x; a.y += c.y; a.z += c.z; a.w += c.w;
            red4[tid] = a;
        }
        __syncthreads();
    }
    const float4 Lsum = red4[0];
    const float4 invl = make_float4(1.f / Lsum.x, 1.f / Lsum.y,
                                    1.f / Lsum.z, 1.f / Lsum.w);
    __syncthreads();

    // ---- phase 2: ctx = P @ V ----
    const int d = tid & 63;
    const int part = tid >> 6;
    float a0 = 0.f, a1 = 0.f, a2 = 0.f, a3 = 0.f;
    const float* vbase = vf + ((size_t)(b * L_)) * D_ + h * HD_ + d;
    const int jlo = part << 8;
    for (int jx = 0; jx < 256; ++jx) {
        const int j = jlo + jx;
        const float vj = vbase[(size_t)j * D_];
        const float4 p = *(const float4*)&s_s[j][0];
        a0 += p.x * vj; a1 += p.y * vj; a2 += p.z * vj; a3 += p.w * vj;
    }
    red4[tid] = make_float4(a0, a1, a2, a3);
    __syncthreads();
    if (tid < 64) {
        float4 c0 = red4[tid], c1 = red4[tid + 64], c2 = red4[tid + 128],
               c3 = red4[tid + 192];
        ctx[((size_t)(b * L_ + i0 + 0)) * D_ + h * HD_ + tid] =
            (c0.x + c1.x + c2.x + c3.x) * invl.x;
        ctx[((size_t)(b * L_ + i0 + 1)) * D_ + h * HD_ + tid] =
            (c0.y + c1.y + c2.y + c3.y) * invl.y;
        ctx[((size_t)(b * L_ + i0 + 2)) * D_ + h * HD_ + tid] =
            (c0.z + c1.z + c2.z + c3.z) * invl.z;
        ctx[((size_t)(b * L_ + i0 + 3)) * D_ + h * HD_ + tid] =
            (c0.w + c1.w + c2.w + c3.w) * invl.w;
    }
}

// ---------------------------------------------------------------------------
extern "C" void kernel_launch(void* const* d_in, const int* in_sizes, int n_in,
                              void* d_out, int out_size, void* d_ws,
                              size_t ws_size, hipStream_t stream) {
    // Inputs fp32 (round-1 NaN proved fp32 buffers). Output written as FP32
    // this round — contract says d_out matches the reference's output dtype
    // (float32). Rounds 2-4 wrote bf16 and produced a deterministic scrambled
    // absmax 0.7265625 across three different pipelines — the bf16-write is
    // the shared element under test.
    const float* x   = (const float*)d_in[0];
    const float* Wq  = (const float*)d_in[1];
    const float* bq  = (const float*)d_in[2];
    const float* Wk  = (const float*)d_in[3];
    const float* bk  = (const float*)d_in[4];
    const float* Wv  = (const float*)d_in[5];
    const float* bv  = (const float*)d_in[6];
    const float* Wo  = (const float*)d_in[7];
    const float* bo  = (const float*)d_in[8];
    const float* E   = (const float*)d_in[9];
    float* out = (float*)d_out;

    // ws: rounds 2 vs 3 bit-identical results prove ws_size >= 40.5 MB.
    char* ws = (char*)d_ws;
    const size_t MB = 1024u * 1024u;
    float* qf   = (float*)(ws);             // 8 MB (pre-scaled by 0.125)
    float* kf   = (float*)(ws + 8 * MB);    // 8 MB
    float* vf   = (float*)(ws + 16 * MB);   // 8 MB
    float* ctxf = (float*)(ws + 24 * MB);   // 8 MB
    float* Efz  = (float*)(ws + 32 * MB);   // 0.5 MB (2048x64 fp32)

    const float scale = 0.125f;  // 64^-0.5

    conv_e_kernel<<<512, 256, 0, stream>>>(E, Efz);

    dim3 gg(D_ / 64, (B_ * L_) / 64);  // (16, 32)
    sgemm_bias_kernel<<<gg, 256, 0, stream>>>(x, Wq, bq, qf, scale);
    sgemm_bias_kernel<<<gg, 256, 0, stream>>>(x, Wk, bk, kf, 1.0f);
    sgemm_bias_kernel<<<gg, 256, 0, stream>>>(x, Wv, bv, vf, 1.0f);

    dim3 ga(L_ / 4, B_ * H_);  // (256, 32)
    attn_kernel<<<ga, 256, 0, stream>>>(qf, kf, vf, Efz, ctxf);

    sgemm_bias_kernel<<<gg, 256, 0, stream>>>(ctxf, Wo, bo, out, 1.0f);
}

// Round 6
// 304.306 us; speedup vs baseline: 7.5597x; 7.5597x over previous
//
#include <hip/hip_runtime.h>
#include <hip/hip_bf16.h>

typedef __bf16 bf16_t;
typedef __bf16 bf16x8 __attribute__((ext_vector_type(8)));
typedef float f32x4 __attribute__((ext_vector_type(4)));
typedef unsigned short u16;
typedef u16 u16x8 __attribute__((ext_vector_type(8)));

#define B_ 2
#define L_ 1024
#define D_ 1024
#define H_ 16
#define HD_ 64

static __device__ __forceinline__ bf16x8 cvt8(float4 a, float4 b) {
    bf16x8 o;
    o[0] = (bf16_t)a.x; o[1] = (bf16_t)a.y; o[2] = (bf16_t)a.z; o[3] = (bf16_t)a.w;
    o[4] = (bf16_t)b.x; o[5] = (bf16_t)b.y; o[6] = (bf16_t)b.z; o[7] = (bf16_t)b.w;
    return o;
}

// ---------------------------------------------------------------------------
// E (fp32, 2047x64) -> Eb (bf16, 2048x64) with a prepended zero row.
// rel[i,j] = q_i . E[j-i+L-2]; zero exactly at j-i = 1-L  =>  Eb[j-i+L-1]
// (skew identity re-verified by hand at L=2.)
// ---------------------------------------------------------------------------
__global__ __launch_bounds__(256) void conv_e_kernel(const float* __restrict__ E,
                                                     bf16_t* __restrict__ Eb) {
    int idx = blockIdx.x * 256 + threadIdx.x;
    if (idx < 64) Eb[idx] = (bf16_t)0.f;
    if (idx < 2047 * 64) Eb[64 + idx] = (bf16_t)E[idx];
}

// ---------------------------------------------------------------------------
// MFMA GEMM (fragment layouts HW-validated: r2 MFMA == r4 scalar bit-exact):
//   val[m][n] = (sum_k A[m][k]*W[n][k] + bias[n]) * alpha
// A (2048,1024) fp32, W (1024,1024) fp32 NxK; both cast bf16 during staging.
// MODE 0: out fp32 flat (m,n).  MODE 2: out bf16 in (B*H, L, 64) layout.
// ---------------------------------------------------------------------------
template <int MODE>
__global__ __launch_bounds__(256) void gemm_bias_kernel(
    const float* __restrict__ A, const float* __restrict__ W,
    const float* __restrict__ bias, float* __restrict__ outF,
    bf16_t* __restrict__ outB, float alpha) {
    constexpr int N = D_;
    constexpr int K = D_;
    constexpr int LDT = 40;   // padded LDS stride (bf16)

    __shared__ __align__(16) bf16_t As[64][LDT];
    __shared__ __align__(16) bf16_t Bs[64][LDT];

    const int tid = threadIdx.x;
    const int m0 = blockIdx.y * 64;
    const int n0 = blockIdx.x * 64;
    const int wave = tid >> 6;
    const int lane = tid & 63;
    const int wm = (wave >> 1) << 5;
    const int wn = (wave & 1) << 5;
    const int lrow = lane & 15;
    const int quad = lane >> 4;

    const int ldr = tid >> 2;
    const int c8 = (tid & 3) << 3;

    f32x4 acc[2][2] = {};

    for (int k0 = 0; k0 < K; k0 += 32) {
        {
            const float4 a0 = *(const float4*)&A[(size_t)(m0 + ldr) * K + k0 + c8];
            const float4 a1 = *(const float4*)&A[(size_t)(m0 + ldr) * K + k0 + c8 + 4];
            *(bf16x8*)&As[ldr][c8] = cvt8(a0, a1);
        }
        {
            const float4 b0 = *(const float4*)&W[(size_t)(n0 + ldr) * K + k0 + c8];
            const float4 b1 = *(const float4*)&W[(size_t)(n0 + ldr) * K + k0 + c8 + 4];
            *(bf16x8*)&Bs[ldr][c8] = cvt8(b0, b1);
        }
        __syncthreads();

        bf16x8 af[2], bfr[2];
        af[0]  = *(const bf16x8*)&As[wm + lrow][quad << 3];
        af[1]  = *(const bf16x8*)&As[wm + 16 + lrow][quad << 3];
        bfr[0] = *(const bf16x8*)&Bs[wn + lrow][quad << 3];
        bfr[1] = *(const bf16x8*)&Bs[wn + 16 + lrow][quad << 3];

#pragma unroll
        for (int t = 0; t < 2; ++t)
#pragma unroll
            for (int u = 0; u < 2; ++u)
                acc[t][u] = __builtin_amdgcn_mfma_f32_16x16x32_bf16(
                    af[t], bfr[u], acc[t][u], 0, 0, 0);
        __syncthreads();
    }

#pragma unroll
    for (int t = 0; t < 2; ++t) {
#pragma unroll
        for (int u = 0; u < 2; ++u) {
            const int col = n0 + wn + u * 16 + lrow;
            const float bv = bias[col];
#pragma unroll
            for (int r = 0; r < 4; ++r) {
                const int row = m0 + wm + t * 16 + quad * 4 + r;
                const float val = (acc[t][u][r] + bv) * alpha;
                if (MODE == 0) {
                    outF[(size_t)row * N + col] = val;
                } else {
                    const int b = row >> 10, i = row & 1023;
                    const int h = col >> 6, d = col & 63;
                    outB[((size_t)((b * H_ + h) * L_ + i)) * HD_ + d] = (bf16_t)val;
                }
            }
        }
    }
}

// ---------------------------------------------------------------------------
// MFMA flash attention with fused relative-position bias.
// One block: (bh, 64 Q-rows). One wave: 16 Q-rows. Loop over 16 K/V-tiles.
// S = Q K^T (MFMA, B-frags direct from global).
// rel: R = Q @ Eband^T (MFMA) into wave-private LDS, then S += R[ii][jj-ii+63].
// Online softmax in registers (16-lane shuffle reductions).
// P -> LDS (bf16) -> A-frags; V staged transposed in LDS for B-frags.
// q is pre-scaled by hd^-0.5 (folds reference's (scores+rel)*scale).
// ---------------------------------------------------------------------------
__global__ __launch_bounds__(256) void fattn_kernel(
    const bf16_t* __restrict__ qbh, const bf16_t* __restrict__ kbh,
    const bf16_t* __restrict__ vbh, const bf16_t* __restrict__ Eb,
    float* __restrict__ ctx) {
    __shared__ __align__(16) bf16_t Vt[64][72];    // V^T tile  [d][j]
    __shared__ __align__(16) bf16_t Rs[64][131];   // rel band  [ii][p] (wave-private rows)
    __shared__ __align__(16) bf16_t Ps[64][72];    // P tile    [ii][jj] (wave-private rows)

    const int tid = threadIdx.x;
    const int w = tid >> 6;          // wave 0..3
    const int lane = tid & 63;
    const int q4 = lane >> 4;        // quad 0..3
    const int n = lane & 15;
    const int bh = blockIdx.y;       // 0..31
    const int b = bh >> 4;
    const int h = bh & 15;
    const int i0 = blockIdx.x * 64;

    // Q A-fragments for this wave's 16 rows, held all kernel.
    bf16x8 aq[2];
    {
        const bf16x8* qrow =
            (const bf16x8*)(qbh + ((size_t)bh * L_ + i0 + 16 * w + n) * HD_);
        aq[0] = qrow[q4];        // k = 0..31  (quad*8)
        aq[1] = qrow[4 + q4];    // k = 32..63
    }

    f32x4 o[4] = {};
    float m_r[4] = {-1e30f, -1e30f, -1e30f, -1e30f};
    float l_r[4] = {0.f, 0.f, 0.f, 0.f};

    const int iloc = 16 * w + 4 * q4;   // wave-local row base (+r)

    for (int jt = 0; jt < 16; ++jt) {
        const int j0 = jt * 64;

        // ---- stage V^T tile: Vt[d][j] = V[j0+j][d], conflict-free pairs ----
        {
            const int c = tid >> 5;           // 0..7  -> d0 = 8c
            const int jp = tid & 31;          // 0..31 -> j = 2jp, 2jp+1
            const int d0 = c * 8;
            const u16* vp =
                (const u16*)(vbh + ((size_t)bh * L_ + j0 + 2 * jp) * HD_ + d0);
            const u16x8 va = *(const u16x8*)vp;
            const u16x8 vb = *(const u16x8*)(vp + HD_);
#pragma unroll
            for (int e = 0; e < 8; ++e) {
                *(unsigned int*)&Vt[d0 + e][2 * jp] =
                    (unsigned int)va[e] | ((unsigned int)vb[e] << 16);
            }
        }
        __syncthreads();

        // ---- S = Q K^T ----
        f32x4 s[4] = {};
#pragma unroll
        for (int u = 0; u < 4; ++u) {
#pragma unroll
            for (int kc = 0; kc < 2; ++kc) {
                const bf16x8 bk = *(const bf16x8*)(kbh +
                    ((size_t)bh * L_ + j0 + 16 * u + n) * HD_ + kc * 32 + 8 * q4);
                s[u] = __builtin_amdgcn_mfma_f32_16x16x32_bf16(aq[kc], bk, s[u], 0, 0, 0);
            }
        }

        // ---- R = Q @ Eband^T  (band rows rbase..rbase+127) ----
        const int rbase = j0 - i0 + 960;   // r1 = rbase + p, p = jj - ii + 63
#pragma unroll
        for (int up = 0; up < 8; ++up) {
            f32x4 rc = {};
#pragma unroll
            for (int kc = 0; kc < 2; ++kc) {
                const bf16x8 be = *(const bf16x8*)(Eb +
                    ((size_t)(rbase + 16 * up + n)) * HD_ + kc * 32 + 8 * q4);
                rc = __builtin_amdgcn_mfma_f32_16x16x32_bf16(aq[kc], be, rc, 0, 0, 0);
            }
#pragma unroll
            for (int r = 0; r < 4; ++r)
                Rs[iloc + r][16 * up + n] = (bf16_t)rc[r];
        }

        // ---- add skewed rel band: S[ii][jj] += R[ii][jj - ii + 63] ----
#pragma unroll
        for (int u = 0; u < 4; ++u)
#pragma unroll
            for (int r = 0; r < 4; ++r)
                s[u][r] += (float)Rs[iloc + r][16 * u + n - (iloc + r) + 63];

        // ---- online softmax (rows split over 16-lane groups) ----
#pragma unroll
        for (int r = 0; r < 4; ++r) {
            float mt = fmaxf(fmaxf(s[0][r], s[1][r]), fmaxf(s[2][r], s[3][r]));
            mt = fmaxf(mt, __shfl_xor(mt, 1));
            mt = fmaxf(mt, __shfl_xor(mt, 2));
            mt = fmaxf(mt, __shfl_xor(mt, 4));
            mt = fmaxf(mt, __shfl_xor(mt, 8));
            const float mn = fmaxf(m_r[r], mt);
            const float al = __expf(m_r[r] - mn);
            m_r[r] = mn;
            float ps = 0.f;
#pragma unroll
            for (int u = 0; u < 4; ++u) {
                const float pv = __expf(s[u][r] - mn);
                s[u][r] = pv;
                ps += pv;
            }
            ps += __shfl_xor(ps, 1);
            ps += __shfl_xor(ps, 2);
            ps += __shfl_xor(ps, 4);
            ps += __shfl_xor(ps, 8);
            l_r[r] = l_r[r] * al + ps;
#pragma unroll
            for (int u = 0; u < 4; ++u) o[u][r] *= al;
        }

        // ---- P -> LDS (wave-private rows), then A-frags ----
#pragma unroll
        for (int u = 0; u < 4; ++u)
#pragma unroll
            for (int r = 0; r < 4; ++r)
                Ps[iloc + r][16 * u + n] = (bf16_t)s[u][r];

        bf16x8 pa[2];
        pa[0] = *(const bf16x8*)&Ps[16 * w + n][8 * q4];
        pa[1] = *(const bf16x8*)&Ps[16 * w + n][32 + 8 * q4];

        // ---- O += P V ----
#pragma unroll
        for (int u = 0; u < 4; ++u) {
#pragma unroll
            for (int kc = 0; kc < 2; ++kc) {
                const bf16x8 bv = *(const bf16x8*)&Vt[16 * u + n][kc * 32 + 8 * q4];
                o[u] = __builtin_amdgcn_mfma_f32_16x16x32_bf16(pa[kc], bv, o[u], 0, 0, 0);
            }
        }
        __syncthreads();   // protect Vt before next stage
    }

    // ---- epilogue: ctx[b, i, h*64+d] = O / l ----
    float inv[4];
#pragma unroll
    for (int r = 0; r < 4; ++r) inv[r] = 1.f / l_r[r];
#pragma unroll
    for (int u = 0; u < 4; ++u)
#pragma unroll
        for (int r = 0; r < 4; ++r)
            ctx[((size_t)(b * L_ + i0 + iloc + r)) * D_ + h * HD_ + 16 * u + n] =
                o[u][r] * inv[r];
}

// ---------------------------------------------------------------------------
extern "C" void kernel_launch(void* const* d_in, const int* in_sizes, int n_in,
                              void* d_out, int out_size, void* d_ws,
                              size_t ws_size, hipStream_t stream) {
    const float* x   = (const float*)d_in[0];
    const float* Wq  = (const float*)d_in[1];
    const float* bq  = (const float*)d_in[2];
    const float* Wk  = (const float*)d_in[3];
    const float* bk  = (const float*)d_in[4];
    const float* Wv  = (const float*)d_in[5];
    const float* bv  = (const float*)d_in[6];
    const float* Wo  = (const float*)d_in[7];
    const float* bo  = (const float*)d_in[8];
    const float* E   = (const float*)d_in[9];
    float* out = (float*)d_out;   // fp32 per reference (validated round 5)

    char* ws = (char*)d_ws;
    const size_t MB = 1024u * 1024u;
    bf16_t* qbh  = (bf16_t*)(ws);             // 4 MB (BH,L,64) bf16, pre-scaled
    bf16_t* kbh  = (bf16_t*)(ws + 4 * MB);    // 4 MB
    bf16_t* vbh  = (bf16_t*)(ws + 8 * MB);    // 4 MB
    float*  ctxf = (float*)(ws + 12 * MB);    // 8 MB fp32 (B,L,D)
    bf16_t* Eb   = (bf16_t*)(ws + 20 * MB);   // 0.25 MB (2048x64 bf16)

    const float scale = 0.125f;  // 64^-0.5

    conv_e_kernel<<<512, 256, 0, stream>>>(E, Eb);

    dim3 gg(D_ / 64, (B_ * L_) / 64);  // (16, 32)
    gemm_bias_kernel<2><<<gg, 256, 0, stream>>>(x, Wq, bq, nullptr, qbh, scale);
    gemm_bias_kernel<2><<<gg, 256, 0, stream>>>(x, Wk, bk, nullptr, kbh, 1.0f);
    gemm_bias_kernel<2><<<gg, 256, 0, stream>>>(x, Wv, bv, nullptr, vbh, 1.0f);

    dim3 ga(L_ / 64, B_ * H_);  // (16, 32)
    fattn_kernel<<<ga, 256, 0, stream>>>(qbh, kbh, vbh, Eb, ctxf);

    gemm_bias_kernel<0><<<gg, 256, 0, stream>>>(ctxf, Wo, bo, out, nullptr, 1.0f);
}

// Round 7
// 249.784 us; speedup vs baseline: 9.2098x; 1.2183x over previous
//
#include <hip/hip_runtime.h>
#include <hip/hip_bf16.h>

typedef __bf16 bf16_t;
typedef __bf16 bf16x8 __attribute__((ext_vector_type(8)));
typedef __bf16 bf16x4 __attribute__((ext_vector_type(4)));
typedef float f32x4 __attribute__((ext_vector_type(4)));
typedef unsigned short u16;
typedef u16 u16x8 __attribute__((ext_vector_type(8)));

#define B_ 2
#define L_ 1024
#define D_ 1024
#define H_ 16
#define HD_ 64

// ---------------------------------------------------------------------------
// fp32 -> bf16 cast, 4 elems/thread
// ---------------------------------------------------------------------------
__global__ __launch_bounds__(256) void cast_kernel(const float* __restrict__ src,
                                                   bf16_t* __restrict__ dst,
                                                   int n4) {
    int i = blockIdx.x * 256 + threadIdx.x;
    if (i < n4) {
        const float4 v = ((const float4*)src)[i];
        bf16x4 o;
        o[0] = (bf16_t)v.x; o[1] = (bf16_t)v.y;
        o[2] = (bf16_t)v.z; o[3] = (bf16_t)v.w;
        ((bf16x4*)dst)[i] = o;
    }
}

// ---------------------------------------------------------------------------
// E (fp32, 2047x64) -> Eb (bf16, 2048x64) with a prepended zero row.
// rel[i,j] = q_i . E[j-i+L-2]; zero exactly at j-i = 1-L  =>  Eb[j-i+L-1]
// ---------------------------------------------------------------------------
__global__ __launch_bounds__(256) void conv_e_kernel(const float* __restrict__ E,
                                                     bf16_t* __restrict__ Eb) {
    int idx = blockIdx.x * 256 + threadIdx.x;
    if (idx < 64) Eb[idx] = (bf16_t)0.f;
    if (idx < 2047 * 64) Eb[64 + idx] = (bf16_t)E[idx];
}

// ---------------------------------------------------------------------------
// MFMA GEMM, both operands bf16 (pre-cast), uint4 staging:
//   val[m][n] = (sum_k A[m][k]*W[n][k] + bias[n]) * alpha
// MODE 0: out fp32 flat (m,n).  MODE 2: out bf16 in (B*H, L, 64) layout.
// Fragment layouts HW-validated (r2 MFMA == r4 scalar bit-exact).
// ---------------------------------------------------------------------------
template <int MODE>
__global__ __launch_bounds__(256) void gemm_bias_kernel(
    const bf16_t* __restrict__ A, const bf16_t* __restrict__ W,
    const float* __restrict__ bias, float* __restrict__ outF,
    bf16_t* __restrict__ outB, float alpha) {
    constexpr int N = D_;
    constexpr int K = D_;
    constexpr int LDT = 40;   // padded LDS stride (bf16), rows 80 B

    __shared__ __align__(16) bf16_t As[64][LDT];
    __shared__ __align__(16) bf16_t Bs[64][LDT];

    const int tid = threadIdx.x;
    const int m0 = blockIdx.y * 64;
    const int n0 = blockIdx.x * 64;
    const int wave = tid >> 6;
    const int lane = tid & 63;
    const int wm = (wave >> 1) << 5;
    const int wn = (wave & 1) << 5;
    const int lrow = lane & 15;
    const int quad = lane >> 4;

    const int ldr = tid >> 2;
    const int c8 = (tid & 3) << 3;

    f32x4 acc[2][2] = {};

    for (int k0 = 0; k0 < K; k0 += 32) {
        *(uint4*)&As[ldr][c8] = *(const uint4*)&A[(size_t)(m0 + ldr) * K + k0 + c8];
        *(uint4*)&Bs[ldr][c8] = *(const uint4*)&W[(size_t)(n0 + ldr) * K + k0 + c8];
        __syncthreads();

        bf16x8 af[2], bfr[2];
        af[0]  = *(const bf16x8*)&As[wm + lrow][quad << 3];
        af[1]  = *(const bf16x8*)&As[wm + 16 + lrow][quad << 3];
        bfr[0] = *(const bf16x8*)&Bs[wn + lrow][quad << 3];
        bfr[1] = *(const bf16x8*)&Bs[wn + 16 + lrow][quad << 3];

#pragma unroll
        for (int t = 0; t < 2; ++t)
#pragma unroll
            for (int u = 0; u < 2; ++u)
                acc[t][u] = __builtin_amdgcn_mfma_f32_16x16x32_bf16(
                    af[t], bfr[u], acc[t][u], 0, 0, 0);
        __syncthreads();
    }

#pragma unroll
    for (int t = 0; t < 2; ++t) {
#pragma unroll
        for (int u = 0; u < 2; ++u) {
            const int col = n0 + wn + u * 16 + lrow;
            const float bv = bias[col];
#pragma unroll
            for (int r = 0; r < 4; ++r) {
                const int row = m0 + wm + t * 16 + quad * 4 + r;
                const float val = (acc[t][u][r] + bv) * alpha;
                if (MODE == 0) {
                    outF[(size_t)row * N + col] = val;
                } else {
                    const int b = row >> 10, i = row & 1023;
                    const int h = col >> 6, d = col & 63;
                    outB[((size_t)((b * H_ + h) * L_ + i)) * HD_ + d] = (bf16_t)val;
                }
            }
        }
    }
}

// ---------------------------------------------------------------------------
// MFMA flash attention, intra-block split-K.
// Block: (bh, 32 Q-rows), 4 waves. Wave w: Q-rows 16*(w&1).., K-half (w>>1).
// Per wave per 64-col K-tile: S = Q K^T; rel R = Q @ Eband^T (80-wide band)
// via wave-private LDS skew; online softmax in registers; P->LDS->A-frags;
// V^T staged in LDS. Final cross-wave (jhalf 0/1) merge via LDS.
// q pre-scaled by hd^-0.5. ctx written bf16 (B,L,D).
// ---------------------------------------------------------------------------
__global__ __launch_bounds__(256) void fattn_kernel(
    const bf16_t* __restrict__ qbh, const bf16_t* __restrict__ kbh,
    const bf16_t* __restrict__ vbh, const bf16_t* __restrict__ Eb,
    bf16_t* __restrict__ ctx) {
    // LDS carve: loop phase  [Vt 2x64x72 | Rs 4x16x84 | Ps 4x16x72] = 38400 B
    //            merge phase [Om 4x16x64 f32 @0 | ml 4x16x2 f32 @18432]
    __shared__ __align__(16) char smem[38400];
    bf16_t (*Vt)[64][72] = (bf16_t(*)[64][72])smem;             // [2][64][72]
    bf16_t (*Rs)[16][84] = (bf16_t(*)[16][84])(smem + 18432);   // [4][16][84]
    bf16_t (*Ps)[16][72] = (bf16_t(*)[16][72])(smem + 29184);   // [4][16][72]
    float  (*Om)[16][64] = (float(*)[16][64])smem;              // merge alias
    float  (*ml)[16][2]  = (float(*)[16][2])(smem + 18432);     // merge alias

    const int tid = threadIdx.x;
    const int w = tid >> 6;          // wave 0..3
    const int lane = tid & 63;
    const int q4 = lane >> 4;        // quad 0..3
    const int n = lane & 15;
    const int qh = w & 1;            // Q-half within block
    const int jh = w >> 1;           // K-half
    const int bh = blockIdx.y;       // 0..31
    const int b = bh >> 4;
    const int h = bh & 15;
    const int i0 = blockIdx.x * 32;
    const int ib = i0 + 16 * qh;     // wave's Q-row base

    // Q A-fragments (16 rows), held all kernel.
    bf16x8 aq[2];
    {
        const bf16x8* qrow = (const bf16x8*)(qbh + ((size_t)bh * L_ + ib + n) * HD_);
        aq[0] = qrow[q4];        // k = 0..31
        aq[1] = qrow[4 + q4];    // k = 32..63
    }

    f32x4 o[4] = {};
    float m_r[4] = {-1e30f, -1e30f, -1e30f, -1e30f};
    float l_r[4] = {0.f, 0.f, 0.f, 0.f};

    // Vt staging ids (within this 128-thread K-half; tid>>7 == jh)
    const int jp = tid & 31;           // j pair base 2*jp
    const int cg = (tid >> 5) & 3;     // d0 = 16*cg

    for (int t = 0; t < 8; ++t) {
        const int j0 = (jh * 8 + t) * 64;

        // ---- stage V^T tile for this K-half: Vt[jh][d][j] = V[j0+j][d] ----
        {
            const int d0 = cg * 16;
            const u16* vp = (const u16*)(vbh + ((size_t)bh * L_ + j0 + 2 * jp) * HD_ + d0);
            const u16x8 va = *(const u16x8*)vp;
            const u16x8 vb2 = *(const u16x8*)(vp + HD_);
            const u16x8 vc = *(const u16x8*)(vp + 8);
            const u16x8 vd = *(const u16x8*)(vp + HD_ + 8);
#pragma unroll
            for (int e = 0; e < 8; ++e) {
                *(unsigned int*)&Vt[jh][d0 + e][2 * jp] =
                    (unsigned int)va[e] | ((unsigned int)vb2[e] << 16);
                *(unsigned int*)&Vt[jh][d0 + 8 + e][2 * jp] =
                    (unsigned int)vc[e] | ((unsigned int)vd[e] << 16);
            }
        }
        __syncthreads();

        // ---- S = Q K^T ----
        f32x4 s[4] = {};
#pragma unroll
        for (int u = 0; u < 4; ++u) {
#pragma unroll
            for (int kc = 0; kc < 2; ++kc) {
                const bf16x8 bk = *(const bf16x8*)(kbh +
                    ((size_t)bh * L_ + j0 + 16 * u + n) * HD_ + kc * 32 + 8 * q4);
                s[u] = __builtin_amdgcn_mfma_f32_16x16x32_bf16(aq[kc], bk, s[u], 0, 0, 0);
            }
        }

        // ---- R = Q @ Eband^T (band rows rbase..rbase+79) ----
        // p = jj - ii_local + 15 in [0,78]; r1 = rbase + p
        const int rbase = j0 - ib + 1008;
#pragma unroll
        for (int up = 0; up < 5; ++up) {
            f32x4 rc = {};
#pragma unroll
            for (int kc = 0; kc < 2; ++kc) {
                const bf16x8 be = *(const bf16x8*)(Eb +
                    ((size_t)(rbase + 16 * up + n)) * HD_ + kc * 32 + 8 * q4);
                rc = __builtin_amdgcn_mfma_f32_16x16x32_bf16(aq[kc], be, rc, 0, 0, 0);
            }
#pragma unroll
            for (int r = 0; r < 4; ++r)
                Rs[w][4 * q4 + r][16 * up + n] = (bf16_t)rc[r];
        }

        // ---- skew add: S[ii][jj] += R[ii][jj - ii + 15] (own-wave rows) ----
#pragma unroll
        for (int u = 0; u < 4; ++u)
#pragma unroll
            for (int r = 0; r < 4; ++r)
                s[u][r] += (float)Rs[w][4 * q4 + r][16 * u + n - (4 * q4 + r) + 15];

        // ---- online softmax (rows across 16-lane groups) ----
#pragma unroll
        for (int r = 0; r < 4; ++r) {
            float mt = fmaxf(fmaxf(s[0][r], s[1][r]), fmaxf(s[2][r], s[3][r]));
            mt = fmaxf(mt, __shfl_xor(mt, 1));
            mt = fmaxf(mt, __shfl_xor(mt, 2));
            mt = fmaxf(mt, __shfl_xor(mt, 4));
            mt = fmaxf(mt, __shfl_xor(mt, 8));
            const float mn = fmaxf(m_r[r], mt);
            const float al = __expf(m_r[r] - mn);
            m_r[r] = mn;
            float ps = 0.f;
#pragma unroll
            for (int u = 0; u < 4; ++u) {
                const float pv = __expf(s[u][r] - mn);
                s[u][r] = pv;
                ps += pv;
            }
            ps += __shfl_xor(ps, 1);
            ps += __shfl_xor(ps, 2);
            ps += __shfl_xor(ps, 4);
            ps += __shfl_xor(ps, 8);
            l_r[r] = l_r[r] * al + ps;
#pragma unroll
            for (int u = 0; u < 4; ++u) o[u][r] *= al;
        }

        // ---- P -> LDS (own-wave rows), then A-frags ----
#pragma unroll
        for (int u = 0; u < 4; ++u)
#pragma unroll
            for (int r = 0; r < 4; ++r)
                Ps[w][4 * q4 + r][16 * u + n] = (bf16_t)s[u][r];

        bf16x8 pa[2];
        pa[0] = *(const bf16x8*)&Ps[w][n][8 * q4];
        pa[1] = *(const bf16x8*)&Ps[w][n][32 + 8 * q4];

        // ---- O += P V ----
#pragma unroll
        for (int u = 0; u < 4; ++u) {
#pragma unroll
            for (int kc = 0; kc < 2; ++kc) {
                const bf16x8 bv = *(const bf16x8*)&Vt[jh][16 * u + n][kc * 32 + 8 * q4];
                o[u] = __builtin_amdgcn_mfma_f32_16x16x32_bf16(pa[kc], bv, o[u], 0, 0, 0);
            }
        }
        __syncthreads();   // protect Vt/LDS before next iteration (and merge)
    }

    // ---- cross-wave merge: waves (qh, jh=0) + (qh, jh=1) ----
#pragma unroll
    for (int u = 0; u < 4; ++u)
#pragma unroll
        for (int r = 0; r < 4; ++r)
            Om[w][4 * q4 + r][16 * u + n] = o[u][r];
    if (n == 0) {
#pragma unroll
        for (int r = 0; r < 4; ++r) {
            ml[w][4 * q4 + r][0] = m_r[r];
            ml[w][4 * q4 + r][1] = l_r[r];
        }
    }
    __syncthreads();

    if (jh == 0) {
#pragma unroll
        for (int r = 0; r < 4; ++r) {
            const int row = 4 * q4 + r;
            const float m2 = ml[w + 2][row][0];
            const float l2 = ml[w + 2][row][1];
            const float ms = fmaxf(m_r[r], m2);
            const float a1 = __expf(m_r[r] - ms);
            const float a2 = __expf(m2 - ms);
            const float inv = 1.f / (l_r[r] * a1 + l2 * a2);
#pragma unroll
            for (int u = 0; u < 4; ++u) {
                const float o2 = Om[w + 2][row][16 * u + n];
                ctx[((size_t)(b * L_ + ib + row)) * D_ + h * HD_ + 16 * u + n] =
                    (bf16_t)((o[u][r] * a1 + o2 * a2) * inv);
            }
        }
    }
}

// ---------------------------------------------------------------------------
extern "C" void kernel_launch(void* const* d_in, const int* in_sizes, int n_in,
                              void* d_out, int out_size, void* d_ws,
                              size_t ws_size, hipStream_t stream) {
    const float* x   = (const float*)d_in[0];
    const float* Wq  = (const float*)d_in[1];
    const float* bq  = (const float*)d_in[2];
    const float* Wk  = (const float*)d_in[3];
    const float* bk  = (const float*)d_in[4];
    const float* Wv  = (const float*)d_in[5];
    const float* bv  = (const float*)d_in[6];
    const float* Wo  = (const float*)d_in[7];
    const float* bo  = (const float*)d_in[8];
    const float* E   = (const float*)d_in[9];
    float* out = (float*)d_out;   // fp32 per reference (validated round 5)

    char* ws = (char*)d_ws;
    const size_t MB = 1024u * 1024u;
    bf16_t* xb   = (bf16_t*)(ws);             // 4 MB (2048x1024)
    bf16_t* Wqb  = (bf16_t*)(ws + 4 * MB);    // 2 MB
    bf16_t* Wkb  = (bf16_t*)(ws + 6 * MB);    // 2 MB
    bf16_t* Wvb  = (bf16_t*)(ws + 8 * MB);    // 2 MB
    bf16_t* Wob  = (bf16_t*)(ws + 10 * MB);   // 2 MB
    bf16_t* qbh  = (bf16_t*)(ws + 12 * MB);   // 4 MB (BH,L,64), pre-scaled
    bf16_t* kbh  = (bf16_t*)(ws + 16 * MB);   // 4 MB
    bf16_t* vbh  = (bf16_t*)(ws + 20 * MB);   // 4 MB
    bf16_t* ctxb = (bf16_t*)(ws + 24 * MB);   // 4 MB (B,L,D)
    bf16_t* Eb   = (bf16_t*)(ws + 28 * MB);   // 0.25 MB (2048x64)

    const float scale = 0.125f;  // 64^-0.5

    conv_e_kernel<<<512, 256, 0, stream>>>(E, Eb);
    cast_kernel<<<2048, 256, 0, stream>>>(x, xb, (B_ * L_ * D_) / 4);
    cast_kernel<<<1024, 256, 0, stream>>>(Wq, Wqb, (D_ * D_) / 4);
    cast_kernel<<<1024, 256, 0, stream>>>(Wk, Wkb, (D_ * D_) / 4);
    cast_kernel<<<1024, 256, 0, stream>>>(Wv, Wvb, (D_ * D_) / 4);
    cast_kernel<<<1024, 256, 0, stream>>>(Wo, Wob, (D_ * D_) / 4);

    dim3 gg(D_ / 64, (B_ * L_) / 64);  // (16, 32)
    gemm_bias_kernel<2><<<gg, 256, 0, stream>>>(xb, Wqb, bq, nullptr, qbh, scale);
    gemm_bias_kernel<2><<<gg, 256, 0, stream>>>(xb, Wkb, bk, nullptr, kbh, 1.0f);
    gemm_bias_kernel<2><<<gg, 256, 0, stream>>>(xb, Wvb, bv, nullptr, vbh, 1.0f);

    dim3 ga(L_ / 32, B_ * H_);  // (32, 32) = 1024 blocks
    fattn_kernel<<<ga, 256, 0, stream>>>(qbh, kbh, vbh, Eb, ctxb);

    gemm_bias_kernel<0><<<gg, 256, 0, stream>>>(ctxb, Wob, bo, out, nullptr, 1.0f);
}